// Round 15
// baseline (238.048 us; speedup 1.0000x reference)
//
#include <hip/hip_runtime.h>
#include <hip/hip_bf16.h>
#include <hip/hip_cooperative_groups.h>

namespace cg = cooperative_groups;

// Problem constants (B,C,N fixed by the reference)
#define B_ 32
#define C_ 64
#define N_ 16384
constexpr float BN_INV = 1.0f / (32.0f * 16384.0f);   // 1/(B*N)

typedef float f32x4 __attribute__((ext_vector_type(4)));
typedef short s16x8 __attribute__((ext_vector_type(8)));

// ---- workspace layout (float offsets) ----
constexpr size_t WS_GPART = 0;                               // [512][4096] per-(b,chunk) Gram partials
constexpr size_t WS_RPART = WS_GPART + (size_t)512 * 4096;   // [512][64]   rowsum partials
constexpr size_t WS_G     = WS_RPART + (size_t)512 * 64;     // [32][4096]  per-batch Gram
constexpr size_t WS_RB    = WS_G + (size_t)32 * 4096;        // [32][64]    per-batch rowsums
constexpr size_t WS_V     = WS_RB + (size_t)32 * 64;         // [32][16384] channel means
constexpr size_t WS_W     = WS_V + (size_t)32 * N_;          // [32][64]    w_b
constexpr size_t WS_GBAR  = WS_W + (size_t)32 * 64;          // [4096] raw sum of all G (atomics)
constexpr size_t WS_MBAR  = WS_GBAR + 4096;                  // [64]   raw sum of all rowsums

__device__ constexpr int P1I[10] = {0,0,0,0,1,1,1,2,2,3};
__device__ constexpr int P1J[10] = {0,1,2,3,1,2,3,2,3,3};
__device__ constexpr int P1AT[4][4] = {{0,1,2,3},{1,4,5,6},{2,5,7,8},{3,6,8,9}};

__device__ __forceinline__ unsigned short bf16_rne_s(float f) {
    unsigned u = __float_as_uint(f);
    unsigned r = u + 0x7FFFu + ((u >> 16) & 1u);
    return (unsigned short)(r >> 16);
}
__device__ __forceinline__ float bf16f(unsigned short u) {
    return __uint_as_float(((unsigned)u) << 16);
}
__device__ __forceinline__ unsigned cvt_pk_bf16(float lo, float hi) {
    unsigned r;
    asm("v_cvt_pk_bf16_f32 %0, %1, %2" : "=v"(r) : "v"(lo), "v"(hi));
    return r;
}
__device__ __forceinline__ void cvt8hi(const f32x4& a, const f32x4& b, s16x8& hi) {
    union { unsigned w[4]; s16x8 v; } u;
    u.w[0] = cvt_pk_bf16(a[0], a[1]);
    u.w[1] = cvt_pk_bf16(a[2], a[3]);
    u.w[2] = cvt_pk_bf16(b[0], b[1]);
    u.w[3] = cvt_pk_bf16(b[2], b[3]);
    hi = u.v;
}

// ============ K1: barrier-free per-wave Gram (hi bf16 MFMA) + v + rowsums ============
__global__ __launch_bounds__(512, 2) void k1(const float* __restrict__ x, float* __restrict__ ws) {
    __shared__ __align__(16) float rawb[4][10 * 256];   // 40 KB
    __shared__ float rws[8][64];
    const int t = threadIdx.x, wv = t >> 6, lane = t & 63;
    const int b = blockIdx.x >> 4, ch = blockIdx.x & 15;
    const int kg = lane >> 4, cl = lane & 15;
    const float* xb = x + ((size_t)b * C_ + cl) * N_ + ch * 1024 + kg * 8;

    // zero the atomic accumulators for this call (phase A adds into them next dispatch)
    if (blockIdx.x == 0) {
        #pragma unroll
        for (int i = 0; i < 8; ++i) ws[WS_GBAR + t * 8 + i] = 0.f;
        if (t < 64) ws[WS_MBAR + t] = 0.f;
    }

    f32x4 accP1[10];
    #pragma unroll
    for (int i = 0; i < 10; ++i) accP1[i] = (f32x4){0.f, 0.f, 0.f, 0.f};
    f32x4 rs = {0.f, 0.f, 0.f, 0.f};

    f32x4 cA[4], cB[4], nA[4], nB[4];
    #pragma unroll
    for (int g = 0; g < 4; ++g) {
        cA[g] = *(const f32x4*)(xb + (size_t)g * (16 * N_) + wv * 32);
        cB[g] = *(const f32x4*)(xb + (size_t)g * (16 * N_) + wv * 32 + 4);
    }

    for (int w = 0; w < 4; ++w) {
        if (w < 3) {
            const int noff = (8 * (w + 1) + wv) * 32;
            #pragma unroll
            for (int g = 0; g < 4; ++g) {
                nA[g] = *(const f32x4*)(xb + (size_t)g * (16 * N_) + noff);
                nB[g] = *(const f32x4*)(xb + (size_t)g * (16 * N_) + noff + 4);
            }
        }
        s16x8 hi[4];
        #pragma unroll
        for (int g = 0; g < 4; ++g) cvt8hi(cA[g], cB[g], hi[g]);

        f32x4 s0 = cA[0] + cA[1] + cA[2] + cA[3];
        f32x4 s1 = cB[0] + cB[1] + cB[2] + cB[3];
        #pragma unroll
        for (int m = 1; m <= 8; m <<= 1) {
            #pragma unroll
            for (int j = 0; j < 4; ++j) {
                s0[j] += __shfl_xor(s0[j], m);
                s1[j] += __shfl_xor(s1[j], m);
            }
        }
        if (cl == 0) {
            float* vp = ws + WS_V + (size_t)b * N_ + ch * 1024 + (8 * w + wv) * 32 + kg * 8;
            *(f32x4*)vp       = s0 * 0.015625f;
            *(f32x4*)(vp + 4) = s1 * 0.015625f;
        }
        #pragma unroll
        for (int g = 0; g < 4; ++g)
            rs[g] += cA[g][0] + cA[g][1] + cA[g][2] + cA[g][3]
                   + cB[g][0] + cB[g][1] + cB[g][2] + cB[g][3];

        #pragma unroll
        for (int i = 0; i < 10; ++i)
            accP1[i] = __builtin_amdgcn_mfma_f32_16x16x32_bf16(hi[P1I[i]], hi[P1J[i]], accP1[i], 0, 0, 0);

        #pragma unroll
        for (int g = 0; g < 4; ++g) { cA[g] = nA[g]; cB[g] = nB[g]; }
    }

    #pragma unroll
    for (int g = 0; g < 4; ++g) {
        rs[g] += __shfl_xor(rs[g], 16);
        rs[g] += __shfl_xor(rs[g], 32);
    }
    if (lane < 16) {
        #pragma unroll
        for (int g = 0; g < 4; ++g) rws[wv][g * 16 + lane] = rs[g];
    }

    if (wv < 4) {
        float* dst = rawb[wv];
        #pragma unroll
        for (int i = 0; i < 10; ++i) *(f32x4*)(dst + i * 256 + lane * 4) = accP1[i];
    }
    __syncthreads();
    if (wv >= 4) {
        float* dst = rawb[wv - 4];
        #pragma unroll
        for (int i = 0; i < 10; ++i) {
            f32x4 o = *(f32x4*)(dst + i * 256 + lane * 4);
            *(f32x4*)(dst + i * 256 + lane * 4) = o + accP1[i];
        }
    }
    __syncthreads();
    if (t < 64) {
        float s = 0.f;
        #pragma unroll
        for (int g = 0; g < 8; ++g) s += rws[g][t];
        ws[WS_RPART + (size_t)blockIdx.x * 64 + t] = s;
    }
    float* gp = ws + WS_GPART + (size_t)blockIdx.x * 4096;
    for (int e = t; e < 4096; e += 512) {
        const int r = e >> 6, c = e & 63;
        const int bi = r >> 4, bj = c >> 4, rr = r & 15, cc = c & 15;
        const int i1 = P1AT[bi][bj] * 256;
        const int o1 = (bi <= bj) ? (((rr >> 2) * 16 + cc) * 4 + (rr & 3))
                                  : (((cc >> 2) * 16 + rr) * 4 + (cc & 3));
        gp[e] = rawb[0][i1 + o1] + rawb[1][i1 + o1] + rawb[2][i1 + o1] + rawb[3][i1 + o1];
    }
}

// ============ Phase bodies (shared by coop kernel and fallback kernels) ============

// Phase A: reduce chunk partials -> per-batch G, RB; atomics -> GBAR, MBAR. Grid: 512 x 256.
__device__ __forceinline__ void phaseA_body(int blk, int t, float* __restrict__ ws) {
    const int b = blk >> 4, sl = blk & 15;
    const int e = sl * 256 + t;
    float s = 0.f;
    #pragma unroll 4
    for (int chn = 0; chn < 16; ++chn) s += ws[WS_GPART + ((size_t)(b * 16 + chn)) * 4096 + e];
    ws[WS_G + (size_t)b * 4096 + e] = s;
    unsafeAtomicAdd(ws + WS_GBAR + e, s);
    if (sl == 0 && t < 64) {
        float s2 = 0.f;
        #pragma unroll 4
        for (int chn = 0; chn < 16; ++chn) s2 += ws[WS_RPART + (size_t)(b * 16 + chn) * 64 + t];
        ws[WS_RB + b * 64 + t] = s2;
        unsafeAtomicAdd(ws + WS_MBAR + t, s2);
    }
}

// Phase B: the R14 C×C chain (5 barriers, wave-specialized). One block per batch.
// OPH = 6 slots of [64*72] ushorts; SV = 11*64 floats.
__device__ __forceinline__ void chain_body(int bb, int t, unsigned short* __restrict__ OPH,
                                           float* __restrict__ SV,
                                           const float* __restrict__ Wq, const float* __restrict__ gamma,
                                           const float* __restrict__ beta, const float* __restrict__ Wq2,
                                           const float* __restrict__ bq2, const float* __restrict__ Wsr,
                                           const float* __restrict__ bsr, const float* __restrict__ Wc,
                                           float* __restrict__ ws) {
    float* quadS = SV;        float* muS = SV + 64;  float* DS  = SV + 128;
    float* abv   = SV + 192;  float* mS  = SV + 256; float* rl  = SV + 320;
    float* ul    = SV + 384;  float* avs = SV + 448; float* sbv = SV + 512;
    float* pls   = SV + 576;  float* aml = SV + 640;
    const int w = t >> 6, lane = t & 63, cl = lane & 15, jg = lane >> 4;
    const int sr = t >> 2, sc0 = (t & 3) * 16;
    auto SLOT = [&](int i) { return OPH + i * 4608; };

    // ---- stage all 5 matrices + vectors ----
    {
        const float* srcs[5] = { ws + WS_GBAR, Wq, Wq2, ws + WS_G + (size_t)bb * 4096, Wsr };
        #pragma unroll
        for (int mI = 0; mI < 5; ++mI) {
            const float sc = (mI == 0) ? BN_INV : 1.f;
            const float* src = srcs[mI] + sr * 64 + sc0;
            s16x8 h8[2];
            #pragma unroll
            for (int q = 0; q < 2; ++q) {
                f32x4 a = *(const f32x4*)(src + q * 8);
                f32x4 b2 = *(const f32x4*)(src + q * 8 + 4);
                #pragma unroll
                for (int j = 0; j < 8; ++j)
                    h8[q][j] = (short)bf16_rne_s(((j < 4) ? a[j] : b2[j - 4]) * sc);
            }
            *(s16x8*)(SLOT(mI) + sr * 72 + sc0)     = h8[0];
            *(s16x8*)(SLOT(mI) + sr * 72 + sc0 + 8) = h8[1];
        }
    }
    if (t < 64) {
        mS[t]  = ws[WS_MBAR + t] * BN_INV;
        rl[t]  = ws[WS_RB + bb * 64 + t];
        sbv[t] = bsr[t];
    }
    __syncthreads();

    // C = Arows · Brows^T stripe: C[row0+jg*4+j][16bj+cl]
    auto mmStripe = [&](const unsigned short* AH, const unsigned short* BH, int row0, f32x4* acc) {
        #pragma unroll
        for (int ks = 0; ks < 2; ++ks) {
            const int ko = ks * 32 + jg * 8;
            s16x8 ah = *(const s16x8*)(AH + (row0 + cl) * 72 + ko);
            #pragma unroll
            for (int bj = 0; bj < 4; ++bj) {
                s16x8 bh = *(const s16x8*)(BH + (16 * bj + cl) * 72 + ko);
                acc[bj] = __builtin_amdgcn_mfma_f32_16x16x32_bf16(ah, bh, acc[bj], 0, 0, 0);
            }
        }
    };

    // ---- Ph1: waves 0-1: Y = Wq·Gbar -> quad; mu0.  waves 2-3: SG = Wsr·G_b^T; pls ----
    if (w < 2) {
        f32x4 acc2[2][4];
        #pragma unroll
        for (int st = 0; st < 2; ++st)
            #pragma unroll
            for (int i = 0; i < 4; ++i) acc2[st][i] = (f32x4){0.f, 0.f, 0.f, 0.f};
        mmStripe(SLOT(1), SLOT(0), 32 * w,      acc2[0]);
        mmStripe(SLOT(1), SLOT(0), 32 * w + 16, acc2[1]);
        #pragma unroll
        for (int st = 0; st < 2; ++st) {
            float s[4] = {0.f, 0.f, 0.f, 0.f};
            #pragma unroll
            for (int j = 0; j < 4; ++j) {
                const int row = 32 * w + 16 * st + jg * 4 + j;
                #pragma unroll
                for (int bj = 0; bj < 4; ++bj)
                    s[j] += acc2[st][bj][j] * bf16f(SLOT(1)[row * 72 + 16 * bj + cl]);
            }
            #pragma unroll
            for (int m = 1; m <= 8; m <<= 1)
                #pragma unroll
                for (int j = 0; j < 4; ++j) s[j] += __shfl_xor(s[j], m);
            if (cl == 0) {
                #pragma unroll
                for (int j = 0; j < 4; ++j) quadS[32 * w + 16 * st + jg * 4 + j] = s[j];
            }
        }
        if (t < 64) {
            float s2 = 0.f;
            #pragma unroll 8
            for (int c = 0; c < 64; ++c) s2 += bf16f(SLOT(1)[t * 72 + c]) * mS[c];
            muS[t] = s2;
        }
    } else {
        const int w2 = w - 2;
        f32x4 acc2[2][4];
        #pragma unroll
        for (int st = 0; st < 2; ++st)
            #pragma unroll
            for (int i = 0; i < 4; ++i) acc2[st][i] = (f32x4){0.f, 0.f, 0.f, 0.f};
        mmStripe(SLOT(4), SLOT(3), 32 * w2,      acc2[0]);   // SG = S·G_b (G symmetric)
        mmStripe(SLOT(4), SLOT(3), 32 * w2 + 16, acc2[1]);
        #pragma unroll
        for (int st = 0; st < 2; ++st)
            #pragma unroll
            for (int bj = 0; bj < 4; ++bj)
                #pragma unroll
                for (int j = 0; j < 4; ++j) {
                    const int row = 32 * w2 + 16 * st + jg * 4 + j, col = 16 * bj + cl;
                    SLOT(5)[row * 72 + col] = (unsigned short)bf16_rne_s(acc2[st][bj][j]);
                }
        const int t2 = t - 128;
        if (t2 < 64 && t2 >= 0) {
            float s = 0.f;
            #pragma unroll 8
            for (int k = 0; k < 64; ++k) s += bf16f(SLOT(4)[t2 * 72 + k]) * rl[k];
            pls[t2] = s + 16384.f * sbv[t2];
        }
    }
    __syncthreads();

    // ---- Ph2: D; (D∘Wq)^T -> slot0; avec ----
    if (t < 64) {
        const float var = quadS[t] - muS[t] * muS[t];
        const float D = gamma[t] * rsqrtf(var + 1e-5f);
        DS[t] = D;
        abv[t] = beta[t] - D * muS[t];
    }
    __syncthreads();
    {
        #pragma unroll
        for (int q = 0; q < 2; ++q) {
            s16x8 h8;
            #pragma unroll
            for (int j = 0; j < 8; ++j) {
                const int c = sc0 + q * 8 + j;
                h8[j] = (short)bf16_rne_s(DS[c] * bf16f(SLOT(1)[c * 72 + sr]));
            }
            *(s16x8*)(SLOT(0) + sr * 72 + sc0 + q * 8) = h8;
        }
    }
    if (t < 64) {
        float s = 0.f;
        #pragma unroll 8
        for (int k = 0; k < 64; ++k) s += bf16f(SLOT(2)[t * 72 + k]) * abv[k];
        avs[t] = s + bq2[t];
    }
    __syncthreads();

    // ---- Ph3: A = Wq2·(DWq); u = A·r; A -> slot1 ----
    {
        f32x4 accA[4];
        #pragma unroll
        for (int i = 0; i < 4; ++i) accA[i] = (f32x4){0.f, 0.f, 0.f, 0.f};
        mmStripe(SLOT(2), SLOT(0), 16 * w, accA);
        float su[4] = {0.f, 0.f, 0.f, 0.f};
        #pragma unroll
        for (int bj = 0; bj < 4; ++bj) {
            const float cv = rl[16 * bj + cl];
            #pragma unroll
            for (int j = 0; j < 4; ++j) su[j] += accA[bj][j] * cv;
        }
        #pragma unroll
        for (int m = 1; m <= 8; m <<= 1)
            #pragma unroll
            for (int j = 0; j < 4; ++j) su[j] += __shfl_xor(su[j], m);
        if (cl == 0) {
            #pragma unroll
            for (int j = 0; j < 4; ++j) ul[16 * w + jg * 4 + j] = su[j];
        }
        #pragma unroll
        for (int bj = 0; bj < 4; ++bj)
            #pragma unroll
            for (int j = 0; j < 4; ++j) {
                const int row = 16 * w + jg * 4 + j, col = 16 * bj + cl;
                SLOT(1)[row * 72 + col] = (unsigned short)bf16_rne_s(accA[bj][j]);
            }
    }
    __syncthreads();

    // ---- Ph4: R = A·SG^T + rank1 = A·G·S^T + rank1; rowmax -> aml ----
    {
        f32x4 acc[4];
        #pragma unroll
        for (int i = 0; i < 4; ++i) acc[i] = (f32x4){0.f, 0.f, 0.f, 0.f};
        mmStripe(SLOT(1), SLOT(5), 16 * w, acc);
        float mx[4] = {-3.4e38f, -3.4e38f, -3.4e38f, -3.4e38f};
        #pragma unroll
        for (int j = 0; j < 4; ++j) {
            const int row = 16 * w + jg * 4 + j;
            const float ur = ul[row], ar = avs[row];
            #pragma unroll
            for (int bj = 0; bj < 4; ++bj) {
                const int col = 16 * bj + cl;
                const float v = acc[bj][j] + ur * sbv[col] + ar * pls[col];
                mx[j] = fmaxf(mx[j], v);
            }
        }
        #pragma unroll
        for (int m = 1; m <= 8; m <<= 1)
            #pragma unroll
            for (int j = 0; j < 4; ++j) mx[j] = fmaxf(mx[j], __shfl_xor(mx[j], m));
        if (cl == 0) {
            #pragma unroll
            for (int j = 0; j < 4; ++j) aml[16 * w + jg * 4 + j] = mx[j];
        }
    }
    __syncthreads();

    // ---- Ph5: w_b = Wc·aml ----
    if (t < 64) {
        float s = 0.f;
        #pragma unroll 8
        for (int c = 0; c < 64; ++c) s += Wc[t * 64 + c] * aml[c];
        ws[WS_W + bb * 64 + t] = s;
    }
}

// Phase C: out[b,o,n] = w[b,o] * v[b,n] (NT stores). Grid: 512 x 256; wls = 64 floats LDS.
__device__ __forceinline__ void phaseC_body(int blk, int t, float* __restrict__ wls,
                                            const float* __restrict__ ws, float* __restrict__ out) {
    const int b = blk >> 4, chk = blk & 15;
    if (t < 64) wls[t] = ws[WS_W + b * 64 + t];
    __syncthreads();
    const size_t nb = (size_t)chk * 1024 + 4 * t;
    const f32x4 v4 = *(const f32x4*)(ws + WS_V + (size_t)b * N_ + nb);
    float* ob = out + (size_t)b * C_ * N_ + nb;
    #pragma unroll
    for (int o = 0; o < 64; ++o) {
        __builtin_nontemporal_store(v4 * wls[o], (f32x4*)(ob + (size_t)o * N_));
    }
}

// ============ K2X: cooperative fused {phaseA, chain, phaseC} — 2 grid.syncs ============
__global__ __launch_bounds__(256, 2) void k2x(const float* __restrict__ Wq, const float* __restrict__ gamma,
                                              const float* __restrict__ beta, const float* __restrict__ Wq2,
                                              const float* __restrict__ bq2, const float* __restrict__ Wsr,
                                              const float* __restrict__ bsr, const float* __restrict__ Wc,
                                              float* __restrict__ ws, float* __restrict__ out) {
    __shared__ __align__(16) unsigned char smem[58112];   // 6*9216 OPH + 11*64*4 SV
    cg::grid_group grid = cg::this_grid();
    const int t = threadIdx.x;

    phaseA_body(blockIdx.x, t, ws);
    __threadfence();
    grid.sync();

    if (blockIdx.x < 32) {
        chain_body(blockIdx.x, t, (unsigned short*)smem, (float*)(smem + 55296),
                   Wq, gamma, beta, Wq2, bq2, Wsr, bsr, Wc, ws);
    }
    __threadfence();
    grid.sync();

    phaseC_body(blockIdx.x, t, (float*)smem, ws, out);
}

// ============ Fallback standalone kernels (R14 path) ============
__global__ __launch_bounds__(256) void k2a(float* __restrict__ ws) {
    phaseA_body(blockIdx.x, threadIdx.x, ws);
}
__global__ __launch_bounds__(256) void k2b(const float* __restrict__ Wq, const float* __restrict__ gamma,
                                           const float* __restrict__ beta, const float* __restrict__ Wq2,
                                           const float* __restrict__ bq2, const float* __restrict__ Wsr,
                                           const float* __restrict__ bsr, const float* __restrict__ Wc,
                                           float* __restrict__ ws) {
    __shared__ __align__(16) unsigned char smem[58112];
    chain_body(blockIdx.x, threadIdx.x, (unsigned short*)smem, (float*)(smem + 55296),
               Wq, gamma, beta, Wq2, bq2, Wsr, bsr, Wc, ws);
}
__global__ __launch_bounds__(256) void k3(const float* __restrict__ ws, float* __restrict__ out) {
    __shared__ float wls[64];
    phaseC_body(blockIdx.x, threadIdx.x, wls, ws, out);
}

extern "C" void kernel_launch(void* const* d_in, const int* in_sizes, int n_in,
                              void* d_out, int out_size, void* d_ws, size_t ws_size,
                              hipStream_t stream) {
    const float* x     = (const float*)d_in[0];
    const float* Wq    = (const float*)d_in[1];
    const float* gamma = (const float*)d_in[3];
    const float* beta  = (const float*)d_in[4];
    const float* Wq2   = (const float*)d_in[5];
    const float* bq2   = (const float*)d_in[6];
    const float* Wsr   = (const float*)d_in[7];
    const float* bsr   = (const float*)d_in[8];
    const float* Wc    = (const float*)d_in[9];
    float* ws  = (float*)d_ws;
    float* out = (float*)d_out;

    hipLaunchKernelGGL(k1, dim3(512), dim3(512), 0, stream, x, ws);

    void* args[] = {(void*)&Wq, (void*)&gamma, (void*)&beta, (void*)&Wq2, (void*)&bq2,
                    (void*)&Wsr, (void*)&bsr, (void*)&Wc, (void*)&ws, (void*)&out};
    hipError_t err = hipLaunchCooperativeKernel((void*)k2x, dim3(512), dim3(256), args, 0, stream);
    if (err != hipSuccess) {
        (void)hipGetLastError();   // clear; fall back to proven 3-kernel chain
        hipLaunchKernelGGL(k2a, dim3(512), dim3(256), 0, stream, ws);
        hipLaunchKernelGGL(k2b, dim3(32),  dim3(256), 0, stream,
                           Wq, gamma, beta, Wq2, bq2, Wsr, bsr, Wc, ws);
        hipLaunchKernelGGL(k3,  dim3(512), dim3(256), 0, stream, ws, out);
    }
}

// Round 16
// 94.554 us; speedup vs baseline: 2.5176x; 2.5176x over previous
//
#include <hip/hip_runtime.h>
#include <hip/hip_bf16.h>
#include <hip/hip_cooperative_groups.h>

namespace cg = cooperative_groups;

// Problem constants (B,C,N fixed by the reference)
#define B_ 32
#define C_ 64
#define N_ 16384
constexpr float BN_INV = 1.0f / (32.0f * 16384.0f);   // 1/(B*N)

typedef float f32x4 __attribute__((ext_vector_type(4)));
typedef short s16x8 __attribute__((ext_vector_type(8)));

// ---- workspace layout (float offsets) ----
constexpr size_t WS_GPART = 0;                               // [512][4096] per-(b,chunk) Gram partials
constexpr size_t WS_RPART = WS_GPART + (size_t)512 * 4096;   // [512][64]   rowsum partials
constexpr size_t WS_G     = WS_RPART + (size_t)512 * 64;     // [32][4096]  (fallback path only)
constexpr size_t WS_RB    = WS_G + (size_t)32 * 4096;        // [32][64]    (fallback path only)
constexpr size_t WS_V     = WS_RB + (size_t)32 * 64;         // [32][16384] channel means
constexpr size_t WS_W     = WS_V + (size_t)32 * N_;          // [32][64]    w_b
constexpr size_t WS_GBAR  = WS_W + (size_t)32 * 64;          // [4096] (fallback)
constexpr size_t WS_MBAR  = WS_GBAR + 4096;                  // [64]   (fallback)
constexpr size_t WS_QUAD  = WS_MBAR + 64;                    // [64]   Σ_b quad_b (atomics)
constexpr size_t WS_MACC  = WS_QUAD + 64;                    // [64]   Σ_b r_b (atomics)

__device__ constexpr int P1I[10] = {0,0,0,0,1,1,1,2,2,3};
__device__ constexpr int P1J[10] = {0,1,2,3,1,2,3,2,3,3};
__device__ constexpr int P1AT[4][4] = {{0,1,2,3},{1,4,5,6},{2,5,7,8},{3,6,8,9}};

__device__ __forceinline__ unsigned short bf16_rne_s(float f) {
    unsigned u = __float_as_uint(f);
    unsigned r = u + 0x7FFFu + ((u >> 16) & 1u);
    return (unsigned short)(r >> 16);
}
__device__ __forceinline__ float bf16f(unsigned short u) {
    return __uint_as_float(((unsigned)u) << 16);
}
__device__ __forceinline__ unsigned cvt_pk_bf16(float lo, float hi) {
    unsigned r;
    asm("v_cvt_pk_bf16_f32 %0, %1, %2" : "=v"(r) : "v"(lo), "v"(hi));
    return r;
}
__device__ __forceinline__ void cvt8hi(const f32x4& a, const f32x4& b, s16x8& hi) {
    union { unsigned w[4]; s16x8 v; } u;
    u.w[0] = cvt_pk_bf16(a[0], a[1]);
    u.w[1] = cvt_pk_bf16(a[2], a[3]);
    u.w[2] = cvt_pk_bf16(b[0], b[1]);
    u.w[3] = cvt_pk_bf16(b[2], b[3]);
    hi = u.v;
}

// ============ K1: barrier-free per-wave Gram (hi bf16 MFMA) + v + rowsums ============
__global__ __launch_bounds__(512, 2) void k1(const float* __restrict__ x, float* __restrict__ ws) {
    __shared__ __align__(16) float rawb[4][10 * 256];   // 40 KB
    __shared__ float rws[8][64];
    const int t = threadIdx.x, wv = t >> 6, lane = t & 63;
    const int b = blockIdx.x >> 4, ch = blockIdx.x & 15;
    const int kg = lane >> 4, cl = lane & 15;
    const float* xb = x + ((size_t)b * C_ + cl) * N_ + ch * 1024 + kg * 8;

    // zero atomic accumulators for this call (consumed by next dispatch)
    if (blockIdx.x == 0) {
        #pragma unroll
        for (int i = 0; i < 8; ++i) ws[WS_GBAR + t * 8 + i] = 0.f;
        if (t < 64) {
            ws[WS_MBAR + t] = 0.f;
            ws[WS_QUAD + t] = 0.f;
            ws[WS_MACC + t] = 0.f;
        }
    }

    f32x4 accP1[10];
    #pragma unroll
    for (int i = 0; i < 10; ++i) accP1[i] = (f32x4){0.f, 0.f, 0.f, 0.f};
    f32x4 rs = {0.f, 0.f, 0.f, 0.f};

    f32x4 cA[4], cB[4], nA[4], nB[4];
    #pragma unroll
    for (int g = 0; g < 4; ++g) {
        cA[g] = *(const f32x4*)(xb + (size_t)g * (16 * N_) + wv * 32);
        cB[g] = *(const f32x4*)(xb + (size_t)g * (16 * N_) + wv * 32 + 4);
    }

    for (int w = 0; w < 4; ++w) {
        if (w < 3) {
            const int noff = (8 * (w + 1) + wv) * 32;
            #pragma unroll
            for (int g = 0; g < 4; ++g) {
                nA[g] = *(const f32x4*)(xb + (size_t)g * (16 * N_) + noff);
                nB[g] = *(const f32x4*)(xb + (size_t)g * (16 * N_) + noff + 4);
            }
        }
        s16x8 hi[4];
        #pragma unroll
        for (int g = 0; g < 4; ++g) cvt8hi(cA[g], cB[g], hi[g]);

        f32x4 s0 = cA[0] + cA[1] + cA[2] + cA[3];
        f32x4 s1 = cB[0] + cB[1] + cB[2] + cB[3];
        #pragma unroll
        for (int m = 1; m <= 8; m <<= 1) {
            #pragma unroll
            for (int j = 0; j < 4; ++j) {
                s0[j] += __shfl_xor(s0[j], m);
                s1[j] += __shfl_xor(s1[j], m);
            }
        }
        if (cl == 0) {
            float* vp = ws + WS_V + (size_t)b * N_ + ch * 1024 + (8 * w + wv) * 32 + kg * 8;
            *(f32x4*)vp       = s0 * 0.015625f;
            *(f32x4*)(vp + 4) = s1 * 0.015625f;
        }
        #pragma unroll
        for (int g = 0; g < 4; ++g)
            rs[g] += cA[g][0] + cA[g][1] + cA[g][2] + cA[g][3]
                   + cB[g][0] + cB[g][1] + cB[g][2] + cB[g][3];

        #pragma unroll
        for (int i = 0; i < 10; ++i)
            accP1[i] = __builtin_amdgcn_mfma_f32_16x16x32_bf16(hi[P1I[i]], hi[P1J[i]], accP1[i], 0, 0, 0);

        #pragma unroll
        for (int g = 0; g < 4; ++g) { cA[g] = nA[g]; cB[g] = nB[g]; }
    }

    #pragma unroll
    for (int g = 0; g < 4; ++g) {
        rs[g] += __shfl_xor(rs[g], 16);
        rs[g] += __shfl_xor(rs[g], 32);
    }
    if (lane < 16) {
        #pragma unroll
        for (int g = 0; g < 4; ++g) rws[wv][g * 16 + lane] = rs[g];
    }

    if (wv < 4) {
        float* dst = rawb[wv];
        #pragma unroll
        for (int i = 0; i < 10; ++i) *(f32x4*)(dst + i * 256 + lane * 4) = accP1[i];
    }
    __syncthreads();
    if (wv >= 4) {
        float* dst = rawb[wv - 4];
        #pragma unroll
        for (int i = 0; i < 10; ++i) {
            f32x4 o = *(f32x4*)(dst + i * 256 + lane * 4);
            *(f32x4*)(dst + i * 256 + lane * 4) = o + accP1[i];
        }
    }
    __syncthreads();
    if (t < 64) {
        float s = 0.f;
        #pragma unroll
        for (int g = 0; g < 8; ++g) s += rws[g][t];
        ws[WS_RPART + (size_t)blockIdx.x * 64 + t] = s;
    }
    float* gp = ws + WS_GPART + (size_t)blockIdx.x * 4096;
    for (int e = t; e < 4096; e += 512) {
        const int r = e >> 6, c = e & 63;
        const int bi = r >> 4, bj = c >> 4, rr = r & 15, cc = c & 15;
        const int i1 = P1AT[bi][bj] * 256;
        const int o1 = (bi <= bj) ? (((rr >> 2) * 16 + cc) * 4 + (rr & 3))
                                  : (((cc >> 2) * 16 + rr) * 4 + (cc & 3));
        gp[e] = rawb[0][i1 + o1] + rawb[1][i1 + o1] + rawb[2][i1 + o1] + rawb[3][i1 + o1];
    }
}

// ============ K2BC: fused reduce + C×C chain (coop, 32 blocks, 1 grid sync) ============
// LDS slots: 0=DWqT, 1=Wq->A, 2=Wq2, 3=G_b, 4=Wsr, 5=SG
__global__ __launch_bounds__(256, 2) void k2bc(const float* __restrict__ Wq, const float* __restrict__ gamma,
                                               const float* __restrict__ beta, const float* __restrict__ Wq2,
                                               const float* __restrict__ bq2, const float* __restrict__ Wsr,
                                               const float* __restrict__ bsr, const float* __restrict__ Wc,
                                               float* __restrict__ ws) {
    __shared__ __align__(16) unsigned short OPH[6][64 * 72];   // 55.3 KB
    __shared__ float quadS[64], muS[64], DS[64], abv[64], mS[64];
    __shared__ float rl[64], ul[64], avs[64], sbv[64], pls[64], aml[64];
    cg::grid_group grid = cg::this_grid();
    const int bb = blockIdx.x, t = threadIdx.x;
    const int w = t >> 6, lane = t & 63, cl = lane & 15, jg = lane >> 4;
    const int sr = t >> 2, sc0 = (t & 3) * 16;

    // ---- Phase 1: reduce own-batch G_b -> slot3; r_b -> rl (+atomic m); stage Wq/Wq2/Wsr ----
    {
        f32x4 s[4];
        #pragma unroll
        for (int j = 0; j < 4; ++j) s[j] = (f32x4){0.f, 0.f, 0.f, 0.f};
        for (int chn = 0; chn < 16; ++chn) {
            const float* gbp = ws + WS_GPART + ((size_t)(bb * 16 + chn)) * 4096 + sr * 64 + sc0;
            #pragma unroll
            for (int j = 0; j < 4; ++j) s[j] += *(const f32x4*)(gbp + 4 * j);
        }
        s16x8 h8[2];
        #pragma unroll
        for (int q = 0; q < 2; ++q)
            #pragma unroll
            for (int j = 0; j < 8; ++j)
                h8[q][j] = (short)bf16_rne_s(s[q * 2 + (j >> 2)][j & 3]);
        *(s16x8*)(&OPH[3][sr * 72 + sc0])     = h8[0];
        *(s16x8*)(&OPH[3][sr * 72 + sc0 + 8]) = h8[1];
    }
    {
        const float* srcs[3] = { Wq, Wq2, Wsr };
        const int slot[3] = {1, 2, 4};
        #pragma unroll
        for (int mI = 0; mI < 3; ++mI) {
            const float* src = srcs[mI] + sr * 64 + sc0;
            s16x8 h8[2];
            #pragma unroll
            for (int q = 0; q < 2; ++q) {
                f32x4 a = *(const f32x4*)(src + q * 8);
                f32x4 b2 = *(const f32x4*)(src + q * 8 + 4);
                #pragma unroll
                for (int j = 0; j < 8; ++j)
                    h8[q][j] = (short)bf16_rne_s((j < 4) ? a[j] : b2[j - 4]);
            }
            *(s16x8*)(&OPH[slot[mI]][sr * 72 + sc0])     = h8[0];
            *(s16x8*)(&OPH[slot[mI]][sr * 72 + sc0 + 8]) = h8[1];
        }
    }
    if (t < 64) {
        float s = 0.f;
        #pragma unroll 4
        for (int chn = 0; chn < 16; ++chn) s += ws[WS_RPART + (size_t)(bb * 16 + chn) * 64 + t];
        rl[t]  = s;
        sbv[t] = bsr[t];
        unsafeAtomicAdd(ws + WS_MACC + t, s);
    }
    __syncthreads();

    // C = Arows · Brows^T stripe: C[row0+jg*4+j][16bj+cl]
    auto mmStripe = [&](const unsigned short* AH, const unsigned short* BH, int row0, f32x4* acc) {
        #pragma unroll
        for (int ks = 0; ks < 2; ++ks) {
            const int ko = ks * 32 + jg * 8;
            s16x8 ah = *(const s16x8*)(AH + (row0 + cl) * 72 + ko);
            #pragma unroll
            for (int bj = 0; bj < 4; ++bj) {
                s16x8 bh = *(const s16x8*)(BH + (16 * bj + cl) * 72 + ko);
                acc[bj] = __builtin_amdgcn_mfma_f32_16x16x32_bf16(ah, bh, acc[bj], 0, 0, 0);
            }
        }
    };

    // ---- Phase 1b: waves 0-1: quad_b = rowdot(Wq·G_b, Wq) -> atomics.
    //                waves 2-3: SG = Wsr·G_b^T (= S·G_b) -> slot5; pls ----
    if (w < 2) {
        f32x4 acc2[2][4];
        #pragma unroll
        for (int st = 0; st < 2; ++st)
            #pragma unroll
            for (int i = 0; i < 4; ++i) acc2[st][i] = (f32x4){0.f, 0.f, 0.f, 0.f};
        mmStripe(OPH[1], OPH[3], 32 * w,      acc2[0]);   // G_b symmetric -> Wq·G_b
        mmStripe(OPH[1], OPH[3], 32 * w + 16, acc2[1]);
        #pragma unroll
        for (int st = 0; st < 2; ++st) {
            float s[4] = {0.f, 0.f, 0.f, 0.f};
            #pragma unroll
            for (int j = 0; j < 4; ++j) {
                const int row = 32 * w + 16 * st + jg * 4 + j;
                #pragma unroll
                for (int bj = 0; bj < 4; ++bj)
                    s[j] += acc2[st][bj][j] * bf16f(OPH[1][row * 72 + 16 * bj + cl]);
            }
            #pragma unroll
            for (int m = 1; m <= 8; m <<= 1)
                #pragma unroll
                for (int j = 0; j < 4; ++j) s[j] += __shfl_xor(s[j], m);
            if (cl == 0) {
                #pragma unroll
                for (int j = 0; j < 4; ++j)
                    unsafeAtomicAdd(ws + WS_QUAD + 32 * w + 16 * st + jg * 4 + j, s[j]);
            }
        }
    } else {
        const int w2 = w - 2;
        f32x4 acc2[2][4];
        #pragma unroll
        for (int st = 0; st < 2; ++st)
            #pragma unroll
            for (int i = 0; i < 4; ++i) acc2[st][i] = (f32x4){0.f, 0.f, 0.f, 0.f};
        mmStripe(OPH[4], OPH[3], 32 * w2,      acc2[0]);
        mmStripe(OPH[4], OPH[3], 32 * w2 + 16, acc2[1]);
        #pragma unroll
        for (int st = 0; st < 2; ++st)
            #pragma unroll
            for (int bj = 0; bj < 4; ++bj)
                #pragma unroll
                for (int j = 0; j < 4; ++j) {
                    const int row = 32 * w2 + 16 * st + jg * 4 + j, col = 16 * bj + cl;
                    OPH[5][row * 72 + col] = (unsigned short)bf16_rne_s(acc2[st][bj][j]);
                }
        const int t2 = t - 128;
        if (t2 < 64 && t2 >= 0) {
            float s = 0.f;
            #pragma unroll 8
            for (int k = 0; k < 64; ++k) s += bf16f(OPH[4][t2 * 72 + k]) * rl[k];
            pls[t2] = s + 16384.f * sbv[t2];
        }
    }
    __threadfence();
    grid.sync();

    // ---- Phase 2a: read global accumulators ----
    if (t < 64) {
        mS[t]    = ws[WS_MACC + t] * BN_INV;
        quadS[t] = ws[WS_QUAD + t] * BN_INV;
    }
    __syncthreads();
    // ---- Phase 2b: mu0 = Wq·m; D; abv ----
    if (t < 64) {
        float s2 = 0.f;
        #pragma unroll 8
        for (int c = 0; c < 64; ++c) s2 += bf16f(OPH[1][t * 72 + c]) * mS[c];
        muS[t] = s2;
        const float var = quadS[t] - s2 * s2;
        const float D = gamma[t] * rsqrtf(var + 1e-5f);
        DS[t] = D;
        abv[t] = beta[t] - D * s2;
    }
    __syncthreads();
    // ---- Phase 2c: (D∘Wq)^T -> slot0; avec ----
    {
        #pragma unroll
        for (int q = 0; q < 2; ++q) {
            s16x8 h8;
            #pragma unroll
            for (int j = 0; j < 8; ++j) {
                const int c = sc0 + q * 8 + j;
                h8[j] = (short)bf16_rne_s(DS[c] * bf16f(OPH[1][c * 72 + sr]));
            }
            *(s16x8*)(&OPH[0][sr * 72 + sc0 + q * 8]) = h8;
        }
    }
    if (t < 64) {
        float s = 0.f;
        #pragma unroll 8
        for (int k = 0; k < 64; ++k) s += bf16f(OPH[2][t * 72 + k]) * abv[k];
        avs[t] = s + bq2[t];
    }
    __syncthreads();

    // ---- Ph3: A = Wq2·(DWq); u = A·r; A -> slot1 ----
    {
        f32x4 accA[4];
        #pragma unroll
        for (int i = 0; i < 4; ++i) accA[i] = (f32x4){0.f, 0.f, 0.f, 0.f};
        mmStripe(OPH[2], OPH[0], 16 * w, accA);
        float su[4] = {0.f, 0.f, 0.f, 0.f};
        #pragma unroll
        for (int bj = 0; bj < 4; ++bj) {
            const float cv = rl[16 * bj + cl];
            #pragma unroll
            for (int j = 0; j < 4; ++j) su[j] += accA[bj][j] * cv;
        }
        #pragma unroll
        for (int m = 1; m <= 8; m <<= 1)
            #pragma unroll
            for (int j = 0; j < 4; ++j) su[j] += __shfl_xor(su[j], m);
        if (cl == 0) {
            #pragma unroll
            for (int j = 0; j < 4; ++j) ul[16 * w + jg * 4 + j] = su[j];
        }
        #pragma unroll
        for (int bj = 0; bj < 4; ++bj)
            #pragma unroll
            for (int j = 0; j < 4; ++j) {
                const int row = 16 * w + jg * 4 + j, col = 16 * bj + cl;
                OPH[1][row * 72 + col] = (unsigned short)bf16_rne_s(accA[bj][j]);
            }
    }
    __syncthreads();

    // ---- Ph4: R = A·SG^T + rank1 = A·G·S^T + rank1; rowmax -> aml ----
    {
        f32x4 acc[4];
        #pragma unroll
        for (int i = 0; i < 4; ++i) acc[i] = (f32x4){0.f, 0.f, 0.f, 0.f};
        mmStripe(OPH[1], OPH[5], 16 * w, acc);
        float mx[4] = {-3.4e38f, -3.4e38f, -3.4e38f, -3.4e38f};
        #pragma unroll
        for (int j = 0; j < 4; ++j) {
            const int row = 16 * w + jg * 4 + j;
            const float ur = ul[row], ar = avs[row];
            #pragma unroll
            for (int bj = 0; bj < 4; ++bj) {
                const int col = 16 * bj + cl;
                const float v = acc[bj][j] + ur * sbv[col] + ar * pls[col];
                mx[j] = fmaxf(mx[j], v);
            }
        }
        #pragma unroll
        for (int m = 1; m <= 8; m <<= 1)
            #pragma unroll
            for (int j = 0; j < 4; ++j) mx[j] = fmaxf(mx[j], __shfl_xor(mx[j], m));
        if (cl == 0) {
            #pragma unroll
            for (int j = 0; j < 4; ++j) aml[16 * w + jg * 4 + j] = mx[j];
        }
    }
    __syncthreads();

    // ---- Ph5: w_b = Wc·aml ----
    if (t < 64) {
        float s = 0.f;
        #pragma unroll 8
        for (int c = 0; c < 64; ++c) s += Wc[t * 64 + c] * aml[c];
        ws[WS_W + bb * 64 + t] = s;
    }
}

// ============ Fallback path: R14's k2a + k2b (proven) ============
__global__ __launch_bounds__(256) void k2a(float* __restrict__ ws) {
    const int b = blockIdx.x >> 3, sl = blockIdx.x & 7, t = threadIdx.x;
    #pragma unroll
    for (int h = 0; h < 2; ++h) {
        const int e = sl * 512 + h * 256 + t;
        float s = 0.f;
        for (int chn = 0; chn < 16; ++chn) s += ws[WS_GPART + ((size_t)(b * 16 + chn)) * 4096 + e];
        ws[WS_G + (size_t)b * 4096 + e] = s;
        unsafeAtomicAdd(ws + WS_GBAR + e, s);
    }
    if (sl == 0 && t < 64) {
        float s = 0.f;
        for (int chn = 0; chn < 16; ++chn) s += ws[WS_RPART + (size_t)(b * 16 + chn) * 64 + t];
        ws[WS_RB + b * 64 + t] = s;
        unsafeAtomicAdd(ws + WS_MBAR + t, s);
    }
}

__global__ __launch_bounds__(256) void k2b(const float* __restrict__ Wq, const float* __restrict__ gamma,
                                           const float* __restrict__ beta, const float* __restrict__ Wq2,
                                           const float* __restrict__ bq2, const float* __restrict__ Wsr,
                                           const float* __restrict__ bsr, const float* __restrict__ Wc,
                                           float* __restrict__ ws) {
    __shared__ __align__(16) unsigned short OPH[6][64 * 72];
    __shared__ float quadS[64], muS[64], DS[64], abv[64], mS[64];
    __shared__ float rl[64], ul[64], avs[64], sbv[64], pls[64], aml[64];
    const int bb = blockIdx.x, t = threadIdx.x;
    const int w = t >> 6, lane = t & 63, cl = lane & 15, jg = lane >> 4;
    const int sr = t >> 2, sc0 = (t & 3) * 16;
    {
        const float* srcs[5] = { ws + WS_GBAR, Wq, Wq2, ws + WS_G + (size_t)bb * 4096, Wsr };
        #pragma unroll
        for (int mI = 0; mI < 5; ++mI) {
            const float sc = (mI == 0) ? BN_INV : 1.f;
            const float* src = srcs[mI] + sr * 64 + sc0;
            s16x8 h8[2];
            #pragma unroll
            for (int q = 0; q < 2; ++q) {
                f32x4 a = *(const f32x4*)(src + q * 8);
                f32x4 b2 = *(const f32x4*)(src + q * 8 + 4);
                #pragma unroll
                for (int j = 0; j < 8; ++j)
                    h8[q][j] = (short)bf16_rne_s(((j < 4) ? a[j] : b2[j - 4]) * sc);
            }
            *(s16x8*)(&OPH[mI][sr * 72 + sc0])     = h8[0];
            *(s16x8*)(&OPH[mI][sr * 72 + sc0 + 8]) = h8[1];
        }
    }
    if (t < 64) {
        mS[t]  = ws[WS_MBAR + t] * BN_INV;
        rl[t]  = ws[WS_RB + bb * 64 + t];
        sbv[t] = bsr[t];
    }
    __syncthreads();
    auto mmStripe = [&](const unsigned short* AH, const unsigned short* BH, int row0, f32x4* acc) {
        #pragma unroll
        for (int ks = 0; ks < 2; ++ks) {
            const int ko = ks * 32 + jg * 8;
            s16x8 ah = *(const s16x8*)(AH + (row0 + cl) * 72 + ko);
            #pragma unroll
            for (int bj = 0; bj < 4; ++bj) {
                s16x8 bh = *(const s16x8*)(BH + (16 * bj + cl) * 72 + ko);
                acc[bj] = __builtin_amdgcn_mfma_f32_16x16x32_bf16(ah, bh, acc[bj], 0, 0, 0);
            }
        }
    };
    if (w < 2) {
        f32x4 acc2[2][4];
        #pragma unroll
        for (int st = 0; st < 2; ++st)
            #pragma unroll
            for (int i = 0; i < 4; ++i) acc2[st][i] = (f32x4){0.f, 0.f, 0.f, 0.f};
        mmStripe(OPH[1], OPH[0], 32 * w,      acc2[0]);
        mmStripe(OPH[1], OPH[0], 32 * w + 16, acc2[1]);
        #pragma unroll
        for (int st = 0; st < 2; ++st) {
            float s[4] = {0.f, 0.f, 0.f, 0.f};
            #pragma unroll
            for (int j = 0; j < 4; ++j) {
                const int row = 32 * w + 16 * st + jg * 4 + j;
                #pragma unroll
                for (int bj = 0; bj < 4; ++bj)
                    s[j] += acc2[st][bj][j] * bf16f(OPH[1][row * 72 + 16 * bj + cl]);
            }
            #pragma unroll
            for (int m = 1; m <= 8; m <<= 1)
                #pragma unroll
                for (int j = 0; j < 4; ++j) s[j] += __shfl_xor(s[j], m);
            if (cl == 0) {
                #pragma unroll
                for (int j = 0; j < 4; ++j) quadS[32 * w + 16 * st + jg * 4 + j] = s[j];
            }
        }
        if (t < 64) {
            float s2 = 0.f;
            #pragma unroll 8
            for (int c = 0; c < 64; ++c) s2 += bf16f(OPH[1][t * 72 + c]) * mS[c];
            muS[t] = s2;
        }
    } else {
        const int w2 = w - 2;
        f32x4 acc2[2][4];
        #pragma unroll
        for (int st = 0; st < 2; ++st)
            #pragma unroll
            for (int i = 0; i < 4; ++i) acc2[st][i] = (f32x4){0.f, 0.f, 0.f, 0.f};
        mmStripe(OPH[4], OPH[3], 32 * w2,      acc2[0]);
        mmStripe(OPH[4], OPH[3], 32 * w2 + 16, acc2[1]);
        #pragma unroll
        for (int st = 0; st < 2; ++st)
            #pragma unroll
            for (int bj = 0; bj < 4; ++bj)
                #pragma unroll
                for (int j = 0; j < 4; ++j) {
                    const int row = 32 * w2 + 16 * st + jg * 4 + j, col = 16 * bj + cl;
                    OPH[5][row * 72 + col] = (unsigned short)bf16_rne_s(acc2[st][bj][j]);
                }
        const int t2 = t - 128;
        if (t2 < 64 && t2 >= 0) {
            float s = 0.f;
            #pragma unroll 8
            for (int k = 0; k < 64; ++k) s += bf16f(OPH[4][t2 * 72 + k]) * rl[k];
            pls[t2] = s + 16384.f * sbv[t2];
        }
    }
    __syncthreads();
    if (t < 64) {
        const float var = quadS[t] - muS[t] * muS[t];
        const float D = gamma[t] * rsqrtf(var + 1e-5f);
        DS[t] = D;
        abv[t] = beta[t] - D * muS[t];
    }
    __syncthreads();
    {
        #pragma unroll
        for (int q = 0; q < 2; ++q) {
            s16x8 h8;
            #pragma unroll
            for (int j = 0; j < 8; ++j) {
                const int c = sc0 + q * 8 + j;
                h8[j] = (short)bf16_rne_s(DS[c] * bf16f(OPH[1][c * 72 + sr]));
            }
            *(s16x8*)(&OPH[0][sr * 72 + sc0 + q * 8]) = h8;
        }
    }
    if (t < 64) {
        float s = 0.f;
        #pragma unroll 8
        for (int k = 0; k < 64; ++k) s += bf16f(OPH[2][t * 72 + k]) * abv[k];
        avs[t] = s + bq2[t];
    }
    __syncthreads();
    {
        f32x4 accA[4];
        #pragma unroll
        for (int i = 0; i < 4; ++i) accA[i] = (f32x4){0.f, 0.f, 0.f, 0.f};
        mmStripe(OPH[2], OPH[0], 16 * w, accA);
        float su[4] = {0.f, 0.f, 0.f, 0.f};
        #pragma unroll
        for (int bj = 0; bj < 4; ++bj) {
            const float cv = rl[16 * bj + cl];
            #pragma unroll
            for (int j = 0; j < 4; ++j) su[j] += accA[bj][j] * cv;
        }
        #pragma unroll
        for (int m = 1; m <= 8; m <<= 1)
            #pragma unroll
            for (int j = 0; j < 4; ++j) su[j] += __shfl_xor(su[j], m);
        if (cl == 0) {
            #pragma unroll
            for (int j = 0; j < 4; ++j) ul[16 * w + jg * 4 + j] = su[j];
        }
        #pragma unroll
        for (int bj = 0; bj < 4; ++bj)
            #pragma unroll
            for (int j = 0; j < 4; ++j) {
                const int row = 16 * w + jg * 4 + j, col = 16 * bj + cl;
                OPH[1][row * 72 + col] = (unsigned short)bf16_rne_s(accA[bj][j]);
            }
    }
    __syncthreads();
    {
        f32x4 acc[4];
        #pragma unroll
        for (int i = 0; i < 4; ++i) acc[i] = (f32x4){0.f, 0.f, 0.f, 0.f};
        mmStripe(OPH[1], OPH[5], 16 * w, acc);
        float mx[4] = {-3.4e38f, -3.4e38f, -3.4e38f, -3.4e38f};
        #pragma unroll
        for (int j = 0; j < 4; ++j) {
            const int row = 16 * w + jg * 4 + j;
            const float ur = ul[row], ar = avs[row];
            #pragma unroll
            for (int bj = 0; bj < 4; ++bj) {
                const int col = 16 * bj + cl;
                const float v = acc[bj][j] + ur * sbv[col] + ar * pls[col];
                mx[j] = fmaxf(mx[j], v);
            }
        }
        #pragma unroll
        for (int m = 1; m <= 8; m <<= 1)
            #pragma unroll
            for (int j = 0; j < 4; ++j) mx[j] = fmaxf(mx[j], __shfl_xor(mx[j], m));
        if (cl == 0) {
            #pragma unroll
            for (int j = 0; j < 4; ++j) aml[16 * w + jg * 4 + j] = mx[j];
        }
    }
    __syncthreads();
    if (t < 64) {
        float s = 0.f;
        #pragma unroll 8
        for (int c = 0; c < 64; ++c) s += Wc[t * 64 + c] * aml[c];
        ws[WS_W + bb * 64 + t] = s;
    }
}

// ============ K3: out[b,o,n] = w[b,o] * v[b,n] (nontemporal, 2048 blocks) ============
__global__ __launch_bounds__(256) void k3(const float* __restrict__ ws, float* __restrict__ out) {
    const int blk = blockIdx.x;
    const int b = blk >> 6, seg = blk & 63;
    const int r0 = (seg >> 4) * 16, chk = seg & 15;
    __shared__ float wls[16];
    const int t = threadIdx.x;
    if (t < 16) wls[t] = ws[WS_W + b * 64 + r0 + t];
    __syncthreads();
    const size_t nb = (size_t)chk * 1024 + 4 * t;
    const f32x4 v4 = *(const f32x4*)(ws + WS_V + (size_t)b * N_ + nb);
    float* ob = out + ((size_t)b * C_ + r0) * N_ + nb;
    #pragma unroll
    for (int o = 0; o < 16; ++o) {
        __builtin_nontemporal_store(v4 * wls[o], (f32x4*)(ob + (size_t)o * N_));
    }
}

extern "C" void kernel_launch(void* const* d_in, const int* in_sizes, int n_in,
                              void* d_out, int out_size, void* d_ws, size_t ws_size,
                              hipStream_t stream) {
    const float* x     = (const float*)d_in[0];
    const float* Wq    = (const float*)d_in[1];
    const float* gamma = (const float*)d_in[3];
    const float* beta  = (const float*)d_in[4];
    const float* Wq2   = (const float*)d_in[5];
    const float* bq2   = (const float*)d_in[6];
    const float* Wsr   = (const float*)d_in[7];
    const float* bsr   = (const float*)d_in[8];
    const float* Wc    = (const float*)d_in[9];
    float* ws  = (float*)d_ws;
    float* out = (float*)d_out;

    hipLaunchKernelGGL(k1, dim3(512), dim3(512), 0, stream, x, ws);

    void* args[] = {(void*)&Wq, (void*)&gamma, (void*)&beta, (void*)&Wq2, (void*)&bq2,
                    (void*)&Wsr, (void*)&bsr, (void*)&Wc, (void*)&ws};
    hipError_t err = hipLaunchCooperativeKernel((void*)k2bc, dim3(32), dim3(256), args, 0, stream);
    if (err != hipSuccess) {
        (void)hipGetLastError();   // clear; fall back to proven R14 chain
        hipLaunchKernelGGL(k2a, dim3(256), dim3(256), 0, stream, ws);
        hipLaunchKernelGGL(k2b, dim3(32),  dim3(256), 0, stream,
                           Wq, gamma, beta, Wq2, bq2, Wsr, bsr, Wc, ws);
    }
    hipLaunchKernelGGL(k3, dim3(2048), dim3(256), 0, stream, ws, out);
}

// Round 17
// 69.664 us; speedup vs baseline: 3.4171x; 1.3573x over previous
//
#include <hip/hip_runtime.h>
#include <hip/hip_bf16.h>

// Problem constants (B,C,N fixed by the reference)
#define B_ 32
#define C_ 64
#define N_ 16384
constexpr float BN_INV = 1.0f / (32.0f * 16384.0f);   // 1/(B*N)

typedef float f32x4 __attribute__((ext_vector_type(4)));
typedef short s16x8 __attribute__((ext_vector_type(8)));

// ---- workspace layout (float offsets) ----
constexpr size_t WS_GPART = 0;                               // [512][4096] per-(b,chunk) Gram partials
constexpr size_t WS_RPART = WS_GPART + (size_t)512 * 4096;   // [512][64]   rowsum partials
constexpr size_t WS_G     = WS_RPART + (size_t)512 * 64;     // [32][4096]  per-batch Gram
constexpr size_t WS_RB    = WS_G + (size_t)32 * 4096;        // [32][64]    per-batch rowsums
constexpr size_t WS_V     = WS_RB + (size_t)32 * 64;         // [32][16384] channel means
constexpr size_t WS_W     = WS_V + (size_t)32 * N_;          // [32][64]    w_b
constexpr size_t WS_GBAR  = WS_W + (size_t)32 * 64;          // [4096] raw sum of all G (atomics)
constexpr size_t WS_MBAR  = WS_GBAR + 4096;                  // [64]   raw sum of all rowsums

__device__ constexpr int P1I[10] = {0,0,0,0,1,1,1,2,2,3};
__device__ constexpr int P1J[10] = {0,1,2,3,1,2,3,2,3,3};
__device__ constexpr int P1AT[4][4] = {{0,1,2,3},{1,4,5,6},{2,5,7,8},{3,6,8,9}};

__device__ __forceinline__ unsigned short bf16_rne_s(float f) {
    unsigned u = __float_as_uint(f);
    unsigned r = u + 0x7FFFu + ((u >> 16) & 1u);
    return (unsigned short)(r >> 16);
}
__device__ __forceinline__ float bf16f(unsigned short u) {
    return __uint_as_float(((unsigned)u) << 16);
}
__device__ __forceinline__ unsigned cvt_pk_bf16(float lo, float hi) {
    unsigned r;
    asm("v_cvt_pk_bf16_f32 %0, %1, %2" : "=v"(r) : "v"(lo), "v"(hi));
    return r;
}
__device__ __forceinline__ void cvt8hi(const f32x4& a, const f32x4& b, s16x8& hi) {
    union { unsigned w[4]; s16x8 v; } u;
    u.w[0] = cvt_pk_bf16(a[0], a[1]);
    u.w[1] = cvt_pk_bf16(a[2], a[3]);
    u.w[2] = cvt_pk_bf16(b[0], b[1]);
    u.w[3] = cvt_pk_bf16(b[2], b[3]);
    hi = u.v;
}

// ============ K1: barrier-free per-wave Gram (hi bf16 MFMA) + v + rowsums ============
__global__ __launch_bounds__(512, 2) void k1(const float* __restrict__ x, float* __restrict__ ws) {
    __shared__ __align__(16) float rawb[4][10 * 256];   // 40 KB
    __shared__ float rws[8][64];
    const int t = threadIdx.x, wv = t >> 6, lane = t & 63;
    const int b = blockIdx.x >> 4, ch = blockIdx.x & 15;
    const int kg = lane >> 4, cl = lane & 15;
    const float* xb = x + ((size_t)b * C_ + cl) * N_ + ch * 1024 + kg * 8;

    // zero the atomic accumulators for this call (k2a adds into them next dispatch)
    if (blockIdx.x == 0) {
        #pragma unroll
        for (int i = 0; i < 8; ++i) ws[WS_GBAR + t * 8 + i] = 0.f;
        if (t < 64) ws[WS_MBAR + t] = 0.f;
    }

    f32x4 accP1[10];
    #pragma unroll
    for (int i = 0; i < 10; ++i) accP1[i] = (f32x4){0.f, 0.f, 0.f, 0.f};
    f32x4 rs = {0.f, 0.f, 0.f, 0.f};

    f32x4 cA[4], cB[4], nA[4], nB[4];
    #pragma unroll
    for (int g = 0; g < 4; ++g) {
        cA[g] = *(const f32x4*)(xb + (size_t)g * (16 * N_) + wv * 32);
        cB[g] = *(const f32x4*)(xb + (size_t)g * (16 * N_) + wv * 32 + 4);
    }

    for (int w = 0; w < 4; ++w) {
        if (w < 3) {
            const int noff = (8 * (w + 1) + wv) * 32;
            #pragma unroll
            for (int g = 0; g < 4; ++g) {
                nA[g] = *(const f32x4*)(xb + (size_t)g * (16 * N_) + noff);
                nB[g] = *(const f32x4*)(xb + (size_t)g * (16 * N_) + noff + 4);
            }
        }
        s16x8 hi[4];
        #pragma unroll
        for (int g = 0; g < 4; ++g) cvt8hi(cA[g], cB[g], hi[g]);

        f32x4 s0 = cA[0] + cA[1] + cA[2] + cA[3];
        f32x4 s1 = cB[0] + cB[1] + cB[2] + cB[3];
        #pragma unroll
        for (int m = 1; m <= 8; m <<= 1) {
            #pragma unroll
            for (int j = 0; j < 4; ++j) {
                s0[j] += __shfl_xor(s0[j], m);
                s1[j] += __shfl_xor(s1[j], m);
            }
        }
        if (cl == 0) {
            float* vp = ws + WS_V + (size_t)b * N_ + ch * 1024 + (8 * w + wv) * 32 + kg * 8;
            *(f32x4*)vp       = s0 * 0.015625f;
            *(f32x4*)(vp + 4) = s1 * 0.015625f;
        }
        #pragma unroll
        for (int g = 0; g < 4; ++g)
            rs[g] += cA[g][0] + cA[g][1] + cA[g][2] + cA[g][3]
                   + cB[g][0] + cB[g][1] + cB[g][2] + cB[g][3];

        #pragma unroll
        for (int i = 0; i < 10; ++i)
            accP1[i] = __builtin_amdgcn_mfma_f32_16x16x32_bf16(hi[P1I[i]], hi[P1J[i]], accP1[i], 0, 0, 0);

        #pragma unroll
        for (int g = 0; g < 4; ++g) { cA[g] = nA[g]; cB[g] = nB[g]; }
    }

    #pragma unroll
    for (int g = 0; g < 4; ++g) {
        rs[g] += __shfl_xor(rs[g], 16);
        rs[g] += __shfl_xor(rs[g], 32);
    }
    if (lane < 16) {
        #pragma unroll
        for (int g = 0; g < 4; ++g) rws[wv][g * 16 + lane] = rs[g];
    }

    if (wv < 4) {
        float* dst = rawb[wv];
        #pragma unroll
        for (int i = 0; i < 10; ++i) *(f32x4*)(dst + i * 256 + lane * 4) = accP1[i];
    }
    __syncthreads();
    if (wv >= 4) {
        float* dst = rawb[wv - 4];
        #pragma unroll
        for (int i = 0; i < 10; ++i) {
            f32x4 o = *(f32x4*)(dst + i * 256 + lane * 4);
            *(f32x4*)(dst + i * 256 + lane * 4) = o + accP1[i];
        }
    }
    __syncthreads();
    if (t < 64) {
        float s = 0.f;
        #pragma unroll
        for (int g = 0; g < 8; ++g) s += rws[g][t];
        ws[WS_RPART + (size_t)blockIdx.x * 64 + t] = s;
    }
    float* gp = ws + WS_GPART + (size_t)blockIdx.x * 4096;
    for (int e = t; e < 4096; e += 512) {
        const int r = e >> 6, c = e & 63;
        const int bi = r >> 4, bj = c >> 4, rr = r & 15, cc = c & 15;
        const int i1 = P1AT[bi][bj] * 256;
        const int o1 = (bi <= bj) ? (((rr >> 2) * 16 + cc) * 4 + (rr & 3))
                                  : (((cc >> 2) * 16 + rr) * 4 + (cc & 3));
        gp[e] = rawb[0][i1 + o1] + rawb[1][i1 + o1] + rawb[2][i1 + o1] + rawb[3][i1 + o1];
    }
}

// ============ K2a: reduce chunk partials -> per-batch G, r; atomics -> Gbar, Mbar ============
__global__ __launch_bounds__(256) void k2a(float* __restrict__ ws) {
    const int b = blockIdx.x >> 3, sl = blockIdx.x & 7, t = threadIdx.x;
    #pragma unroll
    for (int h = 0; h < 2; ++h) {
        const int e = sl * 512 + h * 256 + t;
        float s = 0.f;
        for (int chn = 0; chn < 16; ++chn) s += ws[WS_GPART + ((size_t)(b * 16 + chn)) * 4096 + e];
        ws[WS_G + (size_t)b * 4096 + e] = s;
        unsafeAtomicAdd(ws + WS_GBAR + e, s);
    }
    if (sl == 0 && t < 64) {
        float s = 0.f;
        for (int chn = 0; chn < 16; ++chn) s += ws[WS_RPART + (size_t)(b * 16 + chn) * 64 + t];
        ws[WS_RB + b * 64 + t] = s;
        unsafeAtomicAdd(ws + WS_MBAR + t, s);
    }
}

// ============ K2b: C×C chain, 5 barriers, wave-specialized (32 blocks) ============
// LDS slots: 0=Gbar->DWqT, 1=Wq->A, 2=Wq2, 3=G_b, 4=Wsr, 5=SG (= S·G_b = (G_b·S^T)^T)
__global__ __launch_bounds__(256) void k2b(const float* __restrict__ Wq, const float* __restrict__ gamma,
                                           const float* __restrict__ beta, const float* __restrict__ Wq2,
                                           const float* __restrict__ bq2, const float* __restrict__ Wsr,
                                           const float* __restrict__ bsr, const float* __restrict__ Wc,
                                           float* __restrict__ ws) {
    __shared__ __align__(16) unsigned short OPH[6][64 * 72];   // 55.3 KB
    __shared__ float quadS[64], muS[64], DS[64], abv[64], mS[64];
    __shared__ float rl[64], ul[64], avs[64], sbv[64], pls[64], aml[64];
    const int bb = blockIdx.x, t = threadIdx.x;
    const int w = t >> 6, lane = t & 63, cl = lane & 15, jg = lane >> 4;
    const int sr = t >> 2, sc0 = (t & 3) * 16;

    // ---- stage all 5 matrices + vectors (loads issued up front) ----
    {
        const float* srcs[5] = { ws + WS_GBAR, Wq, Wq2, ws + WS_G + (size_t)bb * 4096, Wsr };
        #pragma unroll
        for (int mI = 0; mI < 5; ++mI) {
            const float sc = (mI == 0) ? BN_INV : 1.f;
            const float* src = srcs[mI] + sr * 64 + sc0;
            s16x8 h8[2];
            #pragma unroll
            for (int q = 0; q < 2; ++q) {
                f32x4 a = *(const f32x4*)(src + q * 8);
                f32x4 b2 = *(const f32x4*)(src + q * 8 + 4);
                #pragma unroll
                for (int j = 0; j < 8; ++j)
                    h8[q][j] = (short)bf16_rne_s(((j < 4) ? a[j] : b2[j - 4]) * sc);
            }
            *(s16x8*)(&OPH[mI][sr * 72 + sc0])     = h8[0];
            *(s16x8*)(&OPH[mI][sr * 72 + sc0 + 8]) = h8[1];
        }
    }
    if (t < 64) {
        mS[t]  = ws[WS_MBAR + t] * BN_INV;
        rl[t]  = ws[WS_RB + bb * 64 + t];
        sbv[t] = bsr[t];
    }
    __syncthreads();

    // C = Arows · Brows^T stripe: C[row0+jg*4+j][16bj+cl]
    auto mmStripe = [&](const unsigned short* AH, const unsigned short* BH, int row0, f32x4* acc) {
        #pragma unroll
        for (int ks = 0; ks < 2; ++ks) {
            const int ko = ks * 32 + jg * 8;
            s16x8 ah = *(const s16x8*)(AH + (row0 + cl) * 72 + ko);
            #pragma unroll
            for (int bj = 0; bj < 4; ++bj) {
                s16x8 bh = *(const s16x8*)(BH + (16 * bj + cl) * 72 + ko);
                acc[bj] = __builtin_amdgcn_mfma_f32_16x16x32_bf16(ah, bh, acc[bj], 0, 0, 0);
            }
        }
    };

    // ---- Ph1: waves 0-1: Y = Wq·Gbar -> quad; mu0.  waves 2-3: SG = Wsr·G_b^T; pls ----
    if (w < 2) {
        f32x4 acc2[2][4];
        #pragma unroll
        for (int st = 0; st < 2; ++st)
            #pragma unroll
            for (int i = 0; i < 4; ++i) acc2[st][i] = (f32x4){0.f, 0.f, 0.f, 0.f};
        mmStripe(OPH[1], OPH[0], 32 * w,      acc2[0]);
        mmStripe(OPH[1], OPH[0], 32 * w + 16, acc2[1]);
        #pragma unroll
        for (int st = 0; st < 2; ++st) {
            float s[4] = {0.f, 0.f, 0.f, 0.f};
            #pragma unroll
            for (int j = 0; j < 4; ++j) {
                const int row = 32 * w + 16 * st + jg * 4 + j;
                #pragma unroll
                for (int bj = 0; bj < 4; ++bj)
                    s[j] += acc2[st][bj][j] * bf16f(OPH[1][row * 72 + 16 * bj + cl]);
            }
            #pragma unroll
            for (int m = 1; m <= 8; m <<= 1)
                #pragma unroll
                for (int j = 0; j < 4; ++j) s[j] += __shfl_xor(s[j], m);
            if (cl == 0) {
                #pragma unroll
                for (int j = 0; j < 4; ++j) quadS[32 * w + 16 * st + jg * 4 + j] = s[j];
            }
        }
        if (t < 64) {
            float s2 = 0.f;
            #pragma unroll 8
            for (int c = 0; c < 64; ++c) s2 += bf16f(OPH[1][t * 72 + c]) * mS[c];
            muS[t] = s2;
        }
    } else {
        const int w2 = w - 2;
        f32x4 acc2[2][4];
        #pragma unroll
        for (int st = 0; st < 2; ++st)
            #pragma unroll
            for (int i = 0; i < 4; ++i) acc2[st][i] = (f32x4){0.f, 0.f, 0.f, 0.f};
        mmStripe(OPH[4], OPH[3], 32 * w2,      acc2[0]);   // SG = S·G_b (G symmetric)
        mmStripe(OPH[4], OPH[3], 32 * w2 + 16, acc2[1]);
        #pragma unroll
        for (int st = 0; st < 2; ++st)
            #pragma unroll
            for (int bj = 0; bj < 4; ++bj)
                #pragma unroll
                for (int j = 0; j < 4; ++j) {
                    const int row = 32 * w2 + 16 * st + jg * 4 + j, col = 16 * bj + cl;
                    OPH[5][row * 72 + col] = (unsigned short)bf16_rne_s(acc2[st][bj][j]);
                }
        const int t2 = t - 128;
        if (t2 < 64 && t2 >= 0) {
            float s = 0.f;
            #pragma unroll 8
            for (int k = 0; k < 64; ++k) s += bf16f(OPH[4][t2 * 72 + k]) * rl[k];
            pls[t2] = s + 16384.f * sbv[t2];
        }
    }
    __syncthreads();

    // ---- Ph2: D; (D∘Wq)^T -> slot0; avec ----
    if (t < 64) {
        const float var = quadS[t] - muS[t] * muS[t];
        const float D = gamma[t] * rsqrtf(var + 1e-5f);
        DS[t] = D;
        abv[t] = beta[t] - D * muS[t];
    }
    __syncthreads();
    {
        #pragma unroll
        for (int q = 0; q < 2; ++q) {
            s16x8 h8;
            #pragma unroll
            for (int j = 0; j < 8; ++j) {
                const int c = sc0 + q * 8 + j;
                h8[j] = (short)bf16_rne_s(DS[c] * bf16f(OPH[1][c * 72 + sr]));
            }
            *(s16x8*)(&OPH[0][sr * 72 + sc0 + q * 8]) = h8;
        }
    }
    if (t < 64) {
        float s = 0.f;
        #pragma unroll 8
        for (int k = 0; k < 64; ++k) s += bf16f(OPH[2][t * 72 + k]) * abv[k];
        avs[t] = s + bq2[t];
    }
    __syncthreads();

    // ---- Ph3: A = Wq2·(DWq); u = A·r; A -> slot1 ----
    {
        f32x4 accA[4];
        #pragma unroll
        for (int i = 0; i < 4; ++i) accA[i] = (f32x4){0.f, 0.f, 0.f, 0.f};
        mmStripe(OPH[2], OPH[0], 16 * w, accA);
        float su[4] = {0.f, 0.f, 0.f, 0.f};
        #pragma unroll
        for (int bj = 0; bj < 4; ++bj) {
            const float cv = rl[16 * bj + cl];
            #pragma unroll
            for (int j = 0; j < 4; ++j) su[j] += accA[bj][j] * cv;
        }
        #pragma unroll
        for (int m = 1; m <= 8; m <<= 1)
            #pragma unroll
            for (int j = 0; j < 4; ++j) su[j] += __shfl_xor(su[j], m);
        if (cl == 0) {
            #pragma unroll
            for (int j = 0; j < 4; ++j) ul[16 * w + jg * 4 + j] = su[j];
        }
        #pragma unroll
        for (int bj = 0; bj < 4; ++bj)
            #pragma unroll
            for (int j = 0; j < 4; ++j) {
                const int row = 16 * w + jg * 4 + j, col = 16 * bj + cl;
                OPH[1][row * 72 + col] = (unsigned short)bf16_rne_s(accA[bj][j]);
            }
    }
    __syncthreads();

    // ---- Ph4: R = A·SG^T + rank1 = A·G·S^T + rank1; rowmax -> aml ----
    {
        f32x4 acc[4];
        #pragma unroll
        for (int i = 0; i < 4; ++i) acc[i] = (f32x4){0.f, 0.f, 0.f, 0.f};
        mmStripe(OPH[1], OPH[5], 16 * w, acc);
        float mx[4] = {-3.4e38f, -3.4e38f, -3.4e38f, -3.4e38f};
        #pragma unroll
        for (int j = 0; j < 4; ++j) {
            const int row = 16 * w + jg * 4 + j;
            const float ur = ul[row], ar = avs[row];
            #pragma unroll
            for (int bj = 0; bj < 4; ++bj) {
                const int col = 16 * bj + cl;
                const float v = acc[bj][j] + ur * sbv[col] + ar * pls[col];
                mx[j] = fmaxf(mx[j], v);
            }
        }
        #pragma unroll
        for (int m = 1; m <= 8; m <<= 1)
            #pragma unroll
            for (int j = 0; j < 4; ++j) mx[j] = fmaxf(mx[j], __shfl_xor(mx[j], m));
        if (cl == 0) {
            #pragma unroll
            for (int j = 0; j < 4; ++j) aml[16 * w + jg * 4 + j] = mx[j];
        }
    }
    __syncthreads();

    // ---- Ph5: w_b = Wc·aml ----
    if (t < 64) {
        float s = 0.f;
        #pragma unroll 8
        for (int c = 0; c < 64; ++c) s += Wc[t * 64 + c] * aml[c];
        ws[WS_W + bb * 64 + t] = s;
    }
}

// ============ K3: out[b,o,n] = w[b,o] * v[b,n] (PLAIN stores — L3 write-back absorbs) ============
__global__ __launch_bounds__(256) void k3(const float* __restrict__ ws, float* __restrict__ out) {
    const int blk = blockIdx.x;
    const int b = blk >> 6, seg = blk & 63;
    const int r0 = (seg >> 4) * 16, chk = seg & 15;
    __shared__ float wls[16];
    const int t = threadIdx.x;
    if (t < 16) wls[t] = ws[WS_W + b * 64 + r0 + t];
    __syncthreads();
    const size_t nb = (size_t)chk * 1024 + 4 * t;
    const f32x4 v4 = *(const f32x4*)(ws + WS_V + (size_t)b * N_ + nb);
    float* ob = out + ((size_t)b * C_ + r0) * N_ + nb;
    #pragma unroll
    for (int o = 0; o < 16; ++o) {
        *((f32x4*)(ob + (size_t)o * N_)) = v4 * wls[o];
    }
}

extern "C" void kernel_launch(void* const* d_in, const int* in_sizes, int n_in,
                              void* d_out, int out_size, void* d_ws, size_t ws_size,
                              hipStream_t stream) {
    const float* x     = (const float*)d_in[0];
    const float* Wq    = (const float*)d_in[1];
    const float* gamma = (const float*)d_in[3];
    const float* beta  = (const float*)d_in[4];
    const float* Wq2   = (const float*)d_in[5];
    const float* bq2   = (const float*)d_in[6];
    const float* Wsr   = (const float*)d_in[7];
    const float* bsr   = (const float*)d_in[8];
    const float* Wc    = (const float*)d_in[9];
    float* ws  = (float*)d_ws;
    float* out = (float*)d_out;

    hipLaunchKernelGGL(k1,  dim3(512),  dim3(512), 0, stream, x, ws);
    hipLaunchKernelGGL(k2a, dim3(256),  dim3(256), 0, stream, ws);
    hipLaunchKernelGGL(k2b, dim3(32),   dim3(256), 0, stream,
                       Wq, gamma, beta, Wq2, bq2, Wsr, bsr, Wc, ws);
    hipLaunchKernelGGL(k3,  dim3(2048), dim3(256), 0, stream, ws, out);
}

// Round 18
// 68.652 us; speedup vs baseline: 3.4675x; 1.0147x over previous
//
#include <hip/hip_runtime.h>
#include <hip/hip_bf16.h>

// Problem constants (B,C,N fixed by the reference)
#define B_ 32
#define C_ 64
#define N_ 16384
constexpr float BN_INV = 1.0f / (32.0f * 16384.0f);   // 1/(B*N)

typedef float f32x4 __attribute__((ext_vector_type(4)));
typedef short s16x8 __attribute__((ext_vector_type(8)));

// ---- workspace layout (float offsets) ----
constexpr size_t WS_GPART = 0;                               // [512][4096] per-(b,chunk) Gram partials
constexpr size_t WS_RPART = WS_GPART + (size_t)512 * 4096;   // [512][64]   rowsum partials
constexpr size_t WS_G     = WS_RPART + (size_t)512 * 64;     // [32][4096]  per-batch Gram
constexpr size_t WS_RB    = WS_G + (size_t)32 * 4096;        // [32][64]    per-batch rowsums
constexpr size_t WS_V     = WS_RB + (size_t)32 * 64;         // [32][16384] channel means
constexpr size_t WS_W     = WS_V + (size_t)32 * N_;          // [32][64]    w_b
constexpr size_t WS_GBAR  = WS_W + (size_t)32 * 64;          // [4096] raw sum of all G (atomics)
constexpr size_t WS_MBAR  = WS_GBAR + 4096;                  // [64]   raw sum of all rowsums

__device__ constexpr int P1I[10] = {0,0,0,0,1,1,1,2,2,3};
__device__ constexpr int P1J[10] = {0,1,2,3,1,2,3,2,3,3};
__device__ constexpr int P1AT[4][4] = {{0,1,2,3},{1,4,5,6},{2,5,7,8},{3,6,8,9}};

__device__ __forceinline__ unsigned short bf16_rne_s(float f) {
    unsigned u = __float_as_uint(f);
    unsigned r = u + 0x7FFFu + ((u >> 16) & 1u);
    return (unsigned short)(r >> 16);
}
__device__ __forceinline__ float bf16f(unsigned short u) {
    return __uint_as_float(((unsigned)u) << 16);
}
__device__ __forceinline__ unsigned cvt_pk_bf16(float lo, float hi) {
    unsigned r;
    asm("v_cvt_pk_bf16_f32 %0, %1, %2" : "=v"(r) : "v"(lo), "v"(hi));
    return r;
}
__device__ __forceinline__ void cvt8hi(const f32x4& a, const f32x4& b, s16x8& hi) {
    union { unsigned w[4]; s16x8 v; } u;
    u.w[0] = cvt_pk_bf16(a[0], a[1]);
    u.w[1] = cvt_pk_bf16(a[2], a[3]);
    u.w[2] = cvt_pk_bf16(b[0], b[1]);
    u.w[3] = cvt_pk_bf16(b[2], b[3]);
    hi = u.v;
}

// ============ K1: barrier-free per-wave Gram (hi bf16 MFMA) + v + rowsums ============
__global__ __launch_bounds__(512, 2) void k1(const float* __restrict__ x, float* __restrict__ ws) {
    __shared__ __align__(16) float rawb[4][10 * 256];   // 40 KB
    __shared__ float rws[8][64];
    const int t = threadIdx.x, wv = t >> 6, lane = t & 63;
    const int b = blockIdx.x >> 4, ch = blockIdx.x & 15;
    const int kg = lane >> 4, cl = lane & 15;
    const float* xb = x + ((size_t)b * C_ + cl) * N_ + ch * 1024 + kg * 8;

    // zero the atomic accumulators for this call (k2a adds into them next dispatch)
    if (blockIdx.x == 0) {
        #pragma unroll
        for (int i = 0; i < 8; ++i) ws[WS_GBAR + t * 8 + i] = 0.f;
        if (t < 64) ws[WS_MBAR + t] = 0.f;
    }

    f32x4 accP1[10];
    #pragma unroll
    for (int i = 0; i < 10; ++i) accP1[i] = (f32x4){0.f, 0.f, 0.f, 0.f};
    f32x4 rs = {0.f, 0.f, 0.f, 0.f};

    f32x4 cA[4], cB[4], nA[4], nB[4];
    #pragma unroll
    for (int g = 0; g < 4; ++g) {
        cA[g] = *(const f32x4*)(xb + (size_t)g * (16 * N_) + wv * 32);
        cB[g] = *(const f32x4*)(xb + (size_t)g * (16 * N_) + wv * 32 + 4);
    }

    for (int w = 0; w < 4; ++w) {
        if (w < 3) {
            const int noff = (8 * (w + 1) + wv) * 32;
            #pragma unroll
            for (int g = 0; g < 4; ++g) {
                nA[g] = *(const f32x4*)(xb + (size_t)g * (16 * N_) + noff);
                nB[g] = *(const f32x4*)(xb + (size_t)g * (16 * N_) + noff + 4);
            }
        }
        s16x8 hi[4];
        #pragma unroll
        for (int g = 0; g < 4; ++g) cvt8hi(cA[g], cB[g], hi[g]);

        f32x4 s0 = cA[0] + cA[1] + cA[2] + cA[3];
        f32x4 s1 = cB[0] + cB[1] + cB[2] + cB[3];
        #pragma unroll
        for (int m = 1; m <= 8; m <<= 1) {
            #pragma unroll
            for (int j = 0; j < 4; ++j) {
                s0[j] += __shfl_xor(s0[j], m);
                s1[j] += __shfl_xor(s1[j], m);
            }
        }
        if (cl == 0) {
            float* vp = ws + WS_V + (size_t)b * N_ + ch * 1024 + (8 * w + wv) * 32 + kg * 8;
            *(f32x4*)vp       = s0 * 0.015625f;
            *(f32x4*)(vp + 4) = s1 * 0.015625f;
        }
        #pragma unroll
        for (int g = 0; g < 4; ++g)
            rs[g] += cA[g][0] + cA[g][1] + cA[g][2] + cA[g][3]
                   + cB[g][0] + cB[g][1] + cB[g][2] + cB[g][3];

        #pragma unroll
        for (int i = 0; i < 10; ++i)
            accP1[i] = __builtin_amdgcn_mfma_f32_16x16x32_bf16(hi[P1I[i]], hi[P1J[i]], accP1[i], 0, 0, 0);

        #pragma unroll
        for (int g = 0; g < 4; ++g) { cA[g] = nA[g]; cB[g] = nB[g]; }
    }

    #pragma unroll
    for (int g = 0; g < 4; ++g) {
        rs[g] += __shfl_xor(rs[g], 16);
        rs[g] += __shfl_xor(rs[g], 32);
    }
    if (lane < 16) {
        #pragma unroll
        for (int g = 0; g < 4; ++g) rws[wv][g * 16 + lane] = rs[g];
    }

    if (wv < 4) {
        float* dst = rawb[wv];
        #pragma unroll
        for (int i = 0; i < 10; ++i) *(f32x4*)(dst + i * 256 + lane * 4) = accP1[i];
    }
    __syncthreads();
    if (wv >= 4) {
        float* dst = rawb[wv - 4];
        #pragma unroll
        for (int i = 0; i < 10; ++i) {
            f32x4 o = *(f32x4*)(dst + i * 256 + lane * 4);
            *(f32x4*)(dst + i * 256 + lane * 4) = o + accP1[i];
        }
    }
    __syncthreads();
    if (t < 64) {
        float s = 0.f;
        #pragma unroll
        for (int g = 0; g < 8; ++g) s += rws[g][t];
        ws[WS_RPART + (size_t)blockIdx.x * 64 + t] = s;
    }
    float* gp = ws + WS_GPART + (size_t)blockIdx.x * 4096;
    for (int e = t; e < 4096; e += 512) {
        const int r = e >> 6, c = e & 63;
        const int bi = r >> 4, bj = c >> 4, rr = r & 15, cc = c & 15;
        const int i1 = P1AT[bi][bj] * 256;
        const int o1 = (bi <= bj) ? (((rr >> 2) * 16 + cc) * 4 + (rr & 3))
                                  : (((cc >> 2) * 16 + rr) * 4 + (cc & 3));
        gp[e] = rawb[0][i1 + o1] + rawb[1][i1 + o1] + rawb[2][i1 + o1] + rawb[3][i1 + o1];
    }
}

// ============ K2a: reduce chunk partials -> per-batch G, r; atomics -> Gbar, Mbar ============
__global__ __launch_bounds__(256) void k2a(float* __restrict__ ws) {
    const int b = blockIdx.x >> 3, sl = blockIdx.x & 7, t = threadIdx.x;
    #pragma unroll
    for (int h = 0; h < 2; ++h) {
        const int e = sl * 512 + h * 256 + t;
        float s = 0.f;
        for (int chn = 0; chn < 16; ++chn) s += ws[WS_GPART + ((size_t)(b * 16 + chn)) * 4096 + e];
        ws[WS_G + (size_t)b * 4096 + e] = s;
        unsafeAtomicAdd(ws + WS_GBAR + e, s);
    }
    if (sl == 0 && t < 64) {
        float s = 0.f;
        for (int chn = 0; chn < 16; ++chn) s += ws[WS_RPART + (size_t)(b * 16 + chn) * 64 + t];
        ws[WS_RB + b * 64 + t] = s;
        unsafeAtomicAdd(ws + WS_MBAR + t, s);
    }
}

// ============ K2b: C×C chain, 5 barriers, wave-specialized (32 blocks) ============
// LDS slots: 0=Gbar->DWqT, 1=Wq->A, 2=Wq2, 3=G_b, 4=Wsr, 5=SG (= S·G_b = (G_b·S^T)^T)
__global__ __launch_bounds__(256) void k2b(const float* __restrict__ Wq, const float* __restrict__ gamma,
                                           const float* __restrict__ beta, const float* __restrict__ Wq2,
                                           const float* __restrict__ bq2, const float* __restrict__ Wsr,
                                           const float* __restrict__ bsr, const float* __restrict__ Wc,
                                           float* __restrict__ ws) {
    __shared__ __align__(16) unsigned short OPH[6][64 * 72];   // 55.3 KB
    __shared__ float quadS[64], muS[64], DS[64], abv[64], mS[64];
    __shared__ float rl[64], ul[64], avs[64], sbv[64], pls[64], aml[64];
    const int bb = blockIdx.x, t = threadIdx.x;
    const int w = t >> 6, lane = t & 63, cl = lane & 15, jg = lane >> 4;
    const int sr = t >> 2, sc0 = (t & 3) * 16;

    // ---- stage all 5 matrices + vectors (loads issued up front) ----
    {
        const float* srcs[5] = { ws + WS_GBAR, Wq, Wq2, ws + WS_G + (size_t)bb * 4096, Wsr };
        #pragma unroll
        for (int mI = 0; mI < 5; ++mI) {
            const float sc = (mI == 0) ? BN_INV : 1.f;
            const float* src = srcs[mI] + sr * 64 + sc0;
            s16x8 h8[2];
            #pragma unroll
            for (int q = 0; q < 2; ++q) {
                f32x4 a = *(const f32x4*)(src + q * 8);
                f32x4 b2 = *(const f32x4*)(src + q * 8 + 4);
                #pragma unroll
                for (int j = 0; j < 8; ++j)
                    h8[q][j] = (short)bf16_rne_s(((j < 4) ? a[j] : b2[j - 4]) * sc);
            }
            *(s16x8*)(&OPH[mI][sr * 72 + sc0])     = h8[0];
            *(s16x8*)(&OPH[mI][sr * 72 + sc0 + 8]) = h8[1];
        }
    }
    if (t < 64) {
        mS[t]  = ws[WS_MBAR + t] * BN_INV;
        rl[t]  = ws[WS_RB + bb * 64 + t];
        sbv[t] = bsr[t];
    }
    __syncthreads();

    // C = Arows · Brows^T stripe: C[row0+jg*4+j][16bj+cl]
    auto mmStripe = [&](const unsigned short* AH, const unsigned short* BH, int row0, f32x4* acc) {
        #pragma unroll
        for (int ks = 0; ks < 2; ++ks) {
            const int ko = ks * 32 + jg * 8;
            s16x8 ah = *(const s16x8*)(AH + (row0 + cl) * 72 + ko);
            #pragma unroll
            for (int bj = 0; bj < 4; ++bj) {
                s16x8 bh = *(const s16x8*)(BH + (16 * bj + cl) * 72 + ko);
                acc[bj] = __builtin_amdgcn_mfma_f32_16x16x32_bf16(ah, bh, acc[bj], 0, 0, 0);
            }
        }
    };

    // ---- Ph1: waves 0-1: Y = Wq·Gbar -> quad; mu0.  waves 2-3: SG = Wsr·G_b^T; pls ----
    if (w < 2) {
        f32x4 acc2[2][4];
        #pragma unroll
        for (int st = 0; st < 2; ++st)
            #pragma unroll
            for (int i = 0; i < 4; ++i) acc2[st][i] = (f32x4){0.f, 0.f, 0.f, 0.f};
        mmStripe(OPH[1], OPH[0], 32 * w,      acc2[0]);
        mmStripe(OPH[1], OPH[0], 32 * w + 16, acc2[1]);
        #pragma unroll
        for (int st = 0; st < 2; ++st) {
            float s[4] = {0.f, 0.f, 0.f, 0.f};
            #pragma unroll
            for (int j = 0; j < 4; ++j) {
                const int row = 32 * w + 16 * st + jg * 4 + j;
                #pragma unroll
                for (int bj = 0; bj < 4; ++bj)
                    s[j] += acc2[st][bj][j] * bf16f(OPH[1][row * 72 + 16 * bj + cl]);
            }
            #pragma unroll
            for (int m = 1; m <= 8; m <<= 1)
                #pragma unroll
                for (int j = 0; j < 4; ++j) s[j] += __shfl_xor(s[j], m);
            if (cl == 0) {
                #pragma unroll
                for (int j = 0; j < 4; ++j) quadS[32 * w + 16 * st + jg * 4 + j] = s[j];
            }
        }
        if (t < 64) {
            float s2 = 0.f;
            #pragma unroll 8
            for (int c = 0; c < 64; ++c) s2 += bf16f(OPH[1][t * 72 + c]) * mS[c];
            muS[t] = s2;
        }
    } else {
        const int w2 = w - 2;
        f32x4 acc2[2][4];
        #pragma unroll
        for (int st = 0; st < 2; ++st)
            #pragma unroll
            for (int i = 0; i < 4; ++i) acc2[st][i] = (f32x4){0.f, 0.f, 0.f, 0.f};
        mmStripe(OPH[4], OPH[3], 32 * w2,      acc2[0]);   // SG = S·G_b (G symmetric)
        mmStripe(OPH[4], OPH[3], 32 * w2 + 16, acc2[1]);
        #pragma unroll
        for (int st = 0; st < 2; ++st)
            #pragma unroll
            for (int bj = 0; bj < 4; ++bj)
                #pragma unroll
                for (int j = 0; j < 4; ++j) {
                    const int row = 32 * w2 + 16 * st + jg * 4 + j, col = 16 * bj + cl;
                    OPH[5][row * 72 + col] = (unsigned short)bf16_rne_s(acc2[st][bj][j]);
                }
        const int t2 = t - 128;
        if (t2 < 64 && t2 >= 0) {
            float s = 0.f;
            #pragma unroll 8
            for (int k = 0; k < 64; ++k) s += bf16f(OPH[4][t2 * 72 + k]) * rl[k];
            pls[t2] = s + 16384.f * sbv[t2];
        }
    }
    __syncthreads();

    // ---- Ph2: D; (D∘Wq)^T -> slot0; avec ----
    if (t < 64) {
        const float var = quadS[t] - muS[t] * muS[t];
        const float D = gamma[t] * rsqrtf(var + 1e-5f);
        DS[t] = D;
        abv[t] = beta[t] - D * muS[t];
    }
    __syncthreads();
    {
        #pragma unroll
        for (int q = 0; q < 2; ++q) {
            s16x8 h8;
            #pragma unroll
            for (int j = 0; j < 8; ++j) {
                const int c = sc0 + q * 8 + j;
                h8[j] = (short)bf16_rne_s(DS[c] * bf16f(OPH[1][c * 72 + sr]));
            }
            *(s16x8*)(&OPH[0][sr * 72 + sc0 + q * 8]) = h8;
        }
    }
    if (t < 64) {
        float s = 0.f;
        #pragma unroll 8
        for (int k = 0; k < 64; ++k) s += bf16f(OPH[2][t * 72 + k]) * abv[k];
        avs[t] = s + bq2[t];
    }
    __syncthreads();

    // ---- Ph3: A = Wq2·(DWq); u = A·r; A -> slot1 ----
    {
        f32x4 accA[4];
        #pragma unroll
        for (int i = 0; i < 4; ++i) accA[i] = (f32x4){0.f, 0.f, 0.f, 0.f};
        mmStripe(OPH[2], OPH[0], 16 * w, accA);
        float su[4] = {0.f, 0.f, 0.f, 0.f};
        #pragma unroll
        for (int bj = 0; bj < 4; ++bj) {
            const float cv = rl[16 * bj + cl];
            #pragma unroll
            for (int j = 0; j < 4; ++j) su[j] += accA[bj][j] * cv;
        }
        #pragma unroll
        for (int m = 1; m <= 8; m <<= 1)
            #pragma unroll
            for (int j = 0; j < 4; ++j) su[j] += __shfl_xor(su[j], m);
        if (cl == 0) {
            #pragma unroll
            for (int j = 0; j < 4; ++j) ul[16 * w + jg * 4 + j] = su[j];
        }
        #pragma unroll
        for (int bj = 0; bj < 4; ++bj)
            #pragma unroll
            for (int j = 0; j < 4; ++j) {
                const int row = 16 * w + jg * 4 + j, col = 16 * bj + cl;
                OPH[1][row * 72 + col] = (unsigned short)bf16_rne_s(accA[bj][j]);
            }
    }
    __syncthreads();

    // ---- Ph4: R = A·SG^T + rank1 = A·G·S^T + rank1; rowmax -> aml ----
    {
        f32x4 acc[4];
        #pragma unroll
        for (int i = 0; i < 4; ++i) acc[i] = (f32x4){0.f, 0.f, 0.f, 0.f};
        mmStripe(OPH[1], OPH[5], 16 * w, acc);
        float mx[4] = {-3.4e38f, -3.4e38f, -3.4e38f, -3.4e38f};
        #pragma unroll
        for (int j = 0; j < 4; ++j) {
            const int row = 16 * w + jg * 4 + j;
            const float ur = ul[row], ar = avs[row];
            #pragma unroll
            for (int bj = 0; bj < 4; ++bj) {
                const int col = 16 * bj + cl;
                const float v = acc[bj][j] + ur * sbv[col] + ar * pls[col];
                mx[j] = fmaxf(mx[j], v);
            }
        }
        #pragma unroll
        for (int m = 1; m <= 8; m <<= 1)
            #pragma unroll
            for (int j = 0; j < 4; ++j) mx[j] = fmaxf(mx[j], __shfl_xor(mx[j], m));
        if (cl == 0) {
            #pragma unroll
            for (int j = 0; j < 4; ++j) aml[16 * w + jg * 4 + j] = mx[j];
        }
    }
    __syncthreads();

    // ---- Ph5: w_b = Wc·aml ----
    if (t < 64) {
        float s = 0.f;
        #pragma unroll 8
        for (int c = 0; c < 64; ++c) s += Wc[t * 64 + c] * aml[c];
        ws[WS_W + bb * 64 + t] = s;
    }
}

// ============ K3: out[b,o,n] = w[b,o] * v[b,n] (nontemporal, 2048 blocks) ============
__global__ __launch_bounds__(256) void k3(const float* __restrict__ ws, float* __restrict__ out) {
    const int blk = blockIdx.x;
    const int b = blk >> 6, seg = blk & 63;
    const int r0 = (seg >> 4) * 16, chk = seg & 15;
    __shared__ float wls[16];
    const int t = threadIdx.x;
    if (t < 16) wls[t] = ws[WS_W + b * 64 + r0 + t];
    __syncthreads();
    const size_t nb = (size_t)chk * 1024 + 4 * t;
    const f32x4 v4 = *(const f32x4*)(ws + WS_V + (size_t)b * N_ + nb);
    float* ob = out + ((size_t)b * C_ + r0) * N_ + nb;
    #pragma unroll
    for (int o = 0; o < 16; ++o) {
        __builtin_nontemporal_store(v4 * wls[o], (f32x4*)(ob + (size_t)o * N_));
    }
}

extern "C" void kernel_launch(void* const* d_in, const int* in_sizes, int n_in,
                              void* d_out, int out_size, void* d_ws, size_t ws_size,
                              hipStream_t stream) {
    const float* x     = (const float*)d_in[0];
    const float* Wq    = (const float*)d_in[1];
    const float* gamma = (const float*)d_in[3];
    const float* beta  = (const float*)d_in[4];
    const float* Wq2   = (const float*)d_in[5];
    const float* bq2   = (const float*)d_in[6];
    const float* Wsr   = (const float*)d_in[7];
    const float* bsr   = (const float*)d_in[8];
    const float* Wc    = (const float*)d_in[9];
    float* ws  = (float*)d_ws;
    float* out = (float*)d_out;

    hipLaunchKernelGGL(k1,  dim3(512),  dim3(512), 0, stream, x, ws);
    hipLaunchKernelGGL(k2a, dim3(256),  dim3(256), 0, stream, ws);
    hipLaunchKernelGGL(k2b, dim3(32),   dim3(256), 0, stream,
                       Wq, gamma, beta, Wq2, bq2, Wsr, bsr, Wc, ws);
    hipLaunchKernelGGL(k3,  dim3(2048), dim3(256), 0, stream, ws, out);
}